// Round 1
// baseline (1067.908 us; speedup 1.0000x reference)
//
#include <hip/hip_runtime.h>

// CapsuleRouting: u (4,288,32,16,14,14) fp32, a unused (dynamic routing variant).
// 3 streaming passes over u (462 MB each) + tiny epilogue kernels.
//
// pass1: norms -> atomic max/min per (c,pos); S0 = sum_B u (atomicAdd)
// v0k  : scale = 1/(max-min); v0 = squash(scale/32 * S0)     [in-place in s0 buf]
// route: r = scale*dot(u, Vr); softmax over C; s += c*scale*u (atomicAdd)
//        (Vr = v0 for iter1; Vr = v0+v1 for iter2 since r accumulates dots)
// v1k  : v1 = squash(s1); s0buf <- v0+v1
// final: v = squash(s2); out = [v (b,C,P,h,w) | a_out (b,C,h,w)]

constexpr int kB    = 4;
constexpr int kIC   = 288;            // input capsules (axis B)
constexpr int kOC   = 32;             // output capsules (axis C)
constexpr int kP    = 16;             // pose
constexpr int kHW   = 196;            // h*w
constexpr int kNPOS = kB * kHW;       // 784
constexpr int kTILE = 16;             // positions per block
constexpr int kNTILES = kNPOS / kTILE; // 49
constexpr int kNCH  = 16;             // B chunks
constexpr int kBCH  = kIC / kNCH;     // 18
constexpr int kSCP  = kOC * kP * kNPOS; // 401408
constexpr int kSC   = kOC * kNPOS;      // 25088
constexpr int kBStride = kOC * kP * kHW; // 100352
constexpr float kEPS = 1e-5f;

__global__ __launch_bounds__(512, 4) void pass1_kernel(
    const float* __restrict__ U, float* __restrict__ s0,
    unsigned int* __restrict__ maxb, unsigned int* __restrict__ minb)
{
    const int tid = threadIdx.x;
    const int pos = tid & (kTILE - 1);
    const int c   = tid >> 4;                 // 0..31
    const int n   = blockIdx.x * kTILE + pos; // flat (b,hw)
    const int b   = n / kHW;
    const int hw  = n - b * kHW;
    const int B0  = blockIdx.y * kBCH;
    const float* up = U + (size_t)(((b * kIC + B0) * kOC + c) * kP) * kHW + hw;

    float sacc[kP];
#pragma unroll
    for (int p = 0; p < kP; ++p) sacc[p] = 0.f;
    float mx = 0.f, mn = 3.4e38f;

    for (int Bi = 0; Bi < kBCH; ++Bi) {
        float u[kP];
#pragma unroll
        for (int p = 0; p < kP; ++p) u[p] = up[p * kHW];
        float nsq = kEPS;
#pragma unroll
        for (int p = 0; p < kP; ++p) { nsq = fmaf(u[p], u[p], nsq); sacc[p] += u[p]; }
        const float nr = sqrtf(nsq);
        mx = fmaxf(mx, nr);
        mn = fminf(mn, nr);
        up += kBStride;
    }
    const int cn = c * kNPOS + n;
    atomicMax(&maxb[cn], __float_as_uint(mx));   // norms > 0: uint order == float order
    atomicMin(&minb[cn], __float_as_uint(mn));
#pragma unroll
    for (int p = 0; p < kP; ++p)
        atomicAdd(&s0[(c * kP + p) * kNPOS + n], sacc[p]);
}

__global__ void v0_kernel(float* __restrict__ s0,
                          const unsigned int* __restrict__ maxb,
                          const unsigned int* __restrict__ minb,
                          float* __restrict__ scaleb)
{
    const int i = blockIdx.x * blockDim.x + threadIdx.x; // c*kNPOS + n
    if (i >= kSC) return;
    const int c = i / kNPOS;
    const int n = i - c * kNPOS;
    const float mx = __uint_as_float(maxb[i]);
    const float mn = __uint_as_float(minb[i]);
    const float sc = 1.f / (mx - mn);
    scaleb[i] = sc;
    float sv[kP];
    float nsq = kEPS;
#pragma unroll
    for (int p = 0; p < kP; ++p) {
        const float v = s0[(c * kP + p) * kNPOS + n] * sc * (1.f / 32.f);
        sv[p] = v;
        nsq = fmaf(v, v, nsq);
    }
    const float inv = 1.f / (1.f + sqrtf(nsq));  // squash: s/(1+||s||)
#pragma unroll
    for (int p = 0; p < kP; ++p)
        s0[(c * kP + p) * kNPOS + n] = sv[p] * inv;
}

__global__ __launch_bounds__(512, 4) void route_kernel(
    const float* __restrict__ U, const float* __restrict__ Vr,
    const float* __restrict__ scaleb, float* __restrict__ sout)
{
    __shared__ float ldsM[8 * kTILE];
    __shared__ float ldsS[8 * kTILE];
    const int tid = threadIdx.x;
    const int pos = tid & (kTILE - 1);
    const int c   = tid >> 4;
    const int wv  = tid >> 6;
    const int n   = blockIdx.x * kTILE + pos;
    const int b   = n / kHW;
    const int hw  = n - b * kHW;
    const int B0  = blockIdx.y * kBCH;
    const float* up = U + (size_t)(((b * kIC + B0) * kOC + c) * kP) * kHW + hw;

    float vr[kP];
#pragma unroll
    for (int p = 0; p < kP; ++p) vr[p] = Vr[(c * kP + p) * kNPOS + n];
    const float sc = scaleb[c * kNPOS + n];

    float acc[kP];
#pragma unroll
    for (int p = 0; p < kP; ++p) acc[p] = 0.f;

    for (int Bi = 0; Bi < kBCH; ++Bi) {
        float u[kP];
#pragma unroll
        for (int p = 0; p < kP; ++p) u[p] = up[p * kHW];
        float d = 0.f;
#pragma unroll
        for (int p = 0; p < kP; ++p) d = fmaf(u[p], vr[p], d);
        const float r = sc * d;

        // softmax over c: 32 c-threads per pos live 4-per-wave across 8 waves
        float m = r;
        m = fmaxf(m, __shfl_xor(m, 16));
        m = fmaxf(m, __shfl_xor(m, 32));
        if ((tid & 63) < kTILE) ldsM[wv * kTILE + pos] = m;
        __syncthreads();
        float mxv = ldsM[pos];
#pragma unroll
        for (int w = 1; w < 8; ++w) mxv = fmaxf(mxv, ldsM[w * kTILE + pos]);

        const float e = __expf(r - mxv);
        float z = e;
        z += __shfl_xor(z, 16);
        z += __shfl_xor(z, 32);
        if ((tid & 63) < kTILE) ldsS[wv * kTILE + pos] = z;
        __syncthreads();
        float Z = ldsS[pos];
#pragma unroll
        for (int w = 1; w < 8; ++w) Z += ldsS[w * kTILE + pos];

        const float cb = e / Z;
#pragma unroll
        for (int p = 0; p < kP; ++p) acc[p] = fmaf(cb, u[p], acc[p]);
        up += kBStride;
    }
#pragma unroll
    for (int p = 0; p < kP; ++p)
        atomicAdd(&sout[(c * kP + p) * kNPOS + n], sc * acc[p]);
}

__global__ void v1_kernel(float* __restrict__ v0buf,   // holds v0; becomes v0+v1
                          const float* __restrict__ s1)
{
    const int i = blockIdx.x * blockDim.x + threadIdx.x;
    if (i >= kSC) return;
    const int c = i / kNPOS;
    const int n = i - c * kNPOS;
    float sv[kP];
    float nsq = kEPS;
#pragma unroll
    for (int p = 0; p < kP; ++p) {
        const float v = s1[(c * kP + p) * kNPOS + n];
        sv[p] = v;
        nsq = fmaf(v, v, nsq);
    }
    const float inv = 1.f / (1.f + sqrtf(nsq));
#pragma unroll
    for (int p = 0; p < kP; ++p)
        v0buf[(c * kP + p) * kNPOS + n] += sv[p] * inv;  // v0 + v1
}

__global__ void final_kernel(const float* __restrict__ s2, float* __restrict__ out)
{
    const int i = blockIdx.x * blockDim.x + threadIdx.x;
    if (i >= kSC) return;
    const int c = i / kNPOS;
    const int n = i - c * kNPOS;
    const int b = n / kHW;
    const int hw = n - b * kHW;
    float sv[kP];
    float nsq = kEPS;
#pragma unroll
    for (int p = 0; p < kP; ++p) {
        const float v = s2[(c * kP + p) * kNPOS + n];
        sv[p] = v;
        nsq = fmaf(v, v, nsq);
    }
    const float inv = 1.f / (1.f + sqrtf(nsq));
    float vs = 0.f;
#pragma unroll
    for (int p = 0; p < kP; ++p) {
        const float v = sv[p] * inv;
        out[(size_t)((b * kOC + c) * kP + p) * kHW + hw] = v;
        vs = fmaf(v, v, vs);
    }
    out[(size_t)kSCP + (b * kOC + c) * kHW + hw] = sqrtf(vs + kEPS);
}

extern "C" void kernel_launch(void* const* d_in, const int* in_sizes, int n_in,
                              void* d_out, int out_size, void* d_ws, size_t ws_size,
                              hipStream_t stream) {
    const float* U = (const float*)d_in[0];
    float* out = (float*)d_out;
    float* ws  = (float*)d_ws;

    float* s0 = ws;                 // kSCP  (S0, then v0, then v0+v1)
    float* s1 = ws + kSCP;          // kSCP
    float* s2 = ws + 2 * kSCP;      // kSCP
    unsigned int* maxb = (unsigned int*)(ws + 3 * kSCP);   // kSC
    unsigned int* minb = maxb + kSC;                       // kSC
    float* scaleb = (float*)(minb + kSC);                  // kSC

    // re-init scratch every call (ws is poisoned 0xAA before each timed launch)
    hipMemsetAsync(s0, 0, (size_t)3 * kSCP * sizeof(float), stream);
    hipMemsetAsync(maxb, 0, (size_t)kSC * sizeof(unsigned int), stream);          // max init 0
    hipMemsetAsync(minb, 0x7F, (size_t)kSC * sizeof(unsigned int), stream);       // 0x7F7F7F7F = 3.39e38

    dim3 grid(kNTILES, kNCH);
    pass1_kernel<<<grid, 512, 0, stream>>>(U, s0, maxb, minb);
    v0_kernel<<<(kSC + 255) / 256, 256, 0, stream>>>(s0, maxb, minb, scaleb);
    route_kernel<<<grid, 512, 0, stream>>>(U, s0, scaleb, s1);
    v1_kernel<<<(kSC + 255) / 256, 256, 0, stream>>>(s0, s1);
    route_kernel<<<grid, 512, 0, stream>>>(U, s0, scaleb, s2);
    final_kernel<<<(kSC + 255) / 256, 256, 0, stream>>>(s2, out);
}

// Round 2
// 1047.593 us; speedup vs baseline: 1.0194x; 1.0194x over previous
//
#include <hip/hip_runtime.h>

// CapsuleRouting: u (4,288,32,16,14,14) fp32, a unused (dynamic routing variant).
// 3 streaming passes over u (462 MB each) + tiny epilogue kernels.
//
// R2 changes vs R1: float2 loads (2 positions/thread -> full 128B line per
// row-chunk per wave), 32-position tiles (25 tiles, last half-predicated),
// flattened grid with XCD swizzle (l&7 = XCD, contiguous hw tiles per XCD).

constexpr int kB    = 4;
constexpr int kIC   = 288;             // input capsules (axis B)
constexpr int kOC   = 32;              // output capsules (axis C)
constexpr int kP    = 16;              // pose
constexpr int kHW   = 196;             // h*w
constexpr int kNPOS = kB * kHW;        // 784
constexpr int kPAIR = 16;              // float2 pairs per block (32 positions)
constexpr int kNTILES = 25;            // ceil(784/32)
constexpr int kNCH  = 16;              // B chunks
constexpr int kBCH  = kIC / kNCH;      // 18
constexpr int kSCP  = kOC * kP * kNPOS; // 401408
constexpr int kSC   = kOC * kNPOS;      // 25088
constexpr int kBStride2 = kOC * kP * kHW / 2; // float2 stride per B: 50176
constexpr int kNBLK = kNTILES * kNCH;  // 400 = 8 * 50
constexpr float kEPS = 1e-5f;

// flat block id -> (tile, chunk) with XCD-contiguous tile ranges.
// XCD g = l&7 gets logical ids [50g, 50g+50) -> ~3 consecutive tiles x all chunks.
__device__ inline void decomp(int l, int& tile, int& chunk) {
    const int logical = (l & 7) * (kNBLK / 8) + (l >> 3);
    tile  = logical >> 4;   // /16
    chunk = logical & 15;
}

__global__ __launch_bounds__(512, 4) void pass1_kernel(
    const float* __restrict__ U, float* __restrict__ s0,
    unsigned int* __restrict__ maxb, unsigned int* __restrict__ minb)
{
    int tile, chunk;
    decomp(blockIdx.x, tile, chunk);
    const int tid = threadIdx.x;
    const int j   = tid & 15;        // pair slot
    const int c   = tid >> 4;        // 0..31
    int n0 = tile * 32 + 2 * j;
    const bool valid = (n0 < kNPOS);
    if (!valid) n0 = kNPOS - 2;
    const int b  = n0 / kHW;
    const int hw = n0 - b * kHW;
    const int B0 = chunk * kBCH;
    const float2* up = (const float2*)(U + (size_t)(((b * kIC + B0) * kOC + c) * kP) * kHW + hw);

    float2 sacc[kP];
#pragma unroll
    for (int p = 0; p < kP; ++p) sacc[p] = make_float2(0.f, 0.f);
    float2 mx = make_float2(0.f, 0.f);
    float2 mn = make_float2(3.4e38f, 3.4e38f);

    for (int Bi = 0; Bi < kBCH; ++Bi) {
        float2 u[kP];
#pragma unroll
        for (int p = 0; p < kP; ++p) u[p] = up[p * (kHW / 2)];
        float2 nsq = make_float2(kEPS, kEPS);
#pragma unroll
        for (int p = 0; p < kP; ++p) {
            nsq.x = fmaf(u[p].x, u[p].x, nsq.x);
            nsq.y = fmaf(u[p].y, u[p].y, nsq.y);
            sacc[p].x += u[p].x;
            sacc[p].y += u[p].y;
        }
        const float nrx = sqrtf(nsq.x), nry = sqrtf(nsq.y);
        mx.x = fmaxf(mx.x, nrx); mx.y = fmaxf(mx.y, nry);
        mn.x = fminf(mn.x, nrx); mn.y = fminf(mn.y, nry);
        up += kBStride2;
    }
    if (valid) {
        const int cn = c * kNPOS + n0;
        atomicMax(&maxb[cn],     __float_as_uint(mx.x));  // norms > 0
        atomicMax(&maxb[cn + 1], __float_as_uint(mx.y));
        atomicMin(&minb[cn],     __float_as_uint(mn.x));
        atomicMin(&minb[cn + 1], __float_as_uint(mn.y));
#pragma unroll
        for (int p = 0; p < kP; ++p) {
            atomicAdd(&s0[(c * kP + p) * kNPOS + n0],     sacc[p].x);
            atomicAdd(&s0[(c * kP + p) * kNPOS + n0 + 1], sacc[p].y);
        }
    }
}

__global__ void v0_kernel(float* __restrict__ s0,
                          const unsigned int* __restrict__ maxb,
                          const unsigned int* __restrict__ minb,
                          float* __restrict__ scaleb)
{
    const int i = blockIdx.x * blockDim.x + threadIdx.x; // c*kNPOS + n
    if (i >= kSC) return;
    const int c = i / kNPOS;
    const int n = i - c * kNPOS;
    const float mx = __uint_as_float(maxb[i]);
    const float mn = __uint_as_float(minb[i]);
    const float sc = 1.f / (mx - mn);
    scaleb[i] = sc;
    float sv[kP];
    float nsq = kEPS;
#pragma unroll
    for (int p = 0; p < kP; ++p) {
        const float v = s0[(c * kP + p) * kNPOS + n] * sc * (1.f / 32.f);
        sv[p] = v;
        nsq = fmaf(v, v, nsq);
    }
    const float inv = 1.f / (1.f + sqrtf(nsq));  // squash: s/(1+||s||)
#pragma unroll
    for (int p = 0; p < kP; ++p)
        s0[(c * kP + p) * kNPOS + n] = sv[p] * inv;
}

__global__ __launch_bounds__(512, 3) void route_kernel(
    const float* __restrict__ U, const float* __restrict__ Vr,
    const float* __restrict__ scaleb, float* __restrict__ sout)
{
    __shared__ float2 ldsM[8 * kPAIR];
    __shared__ float2 ldsS[8 * kPAIR];
    int tile, chunk;
    decomp(blockIdx.x, tile, chunk);
    const int tid = threadIdx.x;
    const int j   = tid & 15;
    const int c   = tid >> 4;
    const int wv  = tid >> 6;
    int n0 = tile * 32 + 2 * j;
    const bool valid = (n0 < kNPOS);
    if (!valid) n0 = kNPOS - 2;
    const int b  = n0 / kHW;
    const int hw = n0 - b * kHW;
    const int B0 = chunk * kBCH;
    const float2* up = (const float2*)(U + (size_t)(((b * kIC + B0) * kOC + c) * kP) * kHW + hw);

    float2 vr[kP];
#pragma unroll
    for (int p = 0; p < kP; ++p)
        vr[p] = *(const float2*)&Vr[(c * kP + p) * kNPOS + n0];
    const float2 sc = *(const float2*)&scaleb[c * kNPOS + n0];

    float2 acc[kP];
#pragma unroll
    for (int p = 0; p < kP; ++p) acc[p] = make_float2(0.f, 0.f);

    for (int Bi = 0; Bi < kBCH; ++Bi) {
        float2 u[kP];
#pragma unroll
        for (int p = 0; p < kP; ++p) u[p] = up[p * (kHW / 2)];
        float2 d = make_float2(0.f, 0.f);
#pragma unroll
        for (int p = 0; p < kP; ++p) {
            d.x = fmaf(u[p].x, vr[p].x, d.x);
            d.y = fmaf(u[p].y, vr[p].y, d.y);
        }
        float2 r = make_float2(sc.x * d.x, sc.y * d.y);

        // softmax over c (32 values): wave has 16 j x 4 c -> shfl over c, LDS over 8 waves
        float2 m = r;
        m.x = fmaxf(m.x, __shfl_xor(m.x, 16)); m.y = fmaxf(m.y, __shfl_xor(m.y, 16));
        m.x = fmaxf(m.x, __shfl_xor(m.x, 32)); m.y = fmaxf(m.y, __shfl_xor(m.y, 32));
        if ((tid & 63) < kPAIR) ldsM[wv * kPAIR + j] = m;
        __syncthreads();
        float2 mxv = ldsM[j];
#pragma unroll
        for (int w = 1; w < 8; ++w) {
            const float2 t = ldsM[w * kPAIR + j];
            mxv.x = fmaxf(mxv.x, t.x); mxv.y = fmaxf(mxv.y, t.y);
        }
        const float2 e = make_float2(__expf(r.x - mxv.x), __expf(r.y - mxv.y));
        float2 z = e;
        z.x += __shfl_xor(z.x, 16); z.y += __shfl_xor(z.y, 16);
        z.x += __shfl_xor(z.x, 32); z.y += __shfl_xor(z.y, 32);
        if ((tid & 63) < kPAIR) ldsS[wv * kPAIR + j] = z;
        __syncthreads();
        float2 Z = ldsS[j];
#pragma unroll
        for (int w = 1; w < 8; ++w) {
            const float2 t = ldsS[w * kPAIR + j];
            Z.x += t.x; Z.y += t.y;
        }
        const float2 cb = make_float2(e.x / Z.x, e.y / Z.y);
#pragma unroll
        for (int p = 0; p < kP; ++p) {
            acc[p].x = fmaf(cb.x, u[p].x, acc[p].x);
            acc[p].y = fmaf(cb.y, u[p].y, acc[p].y);
        }
        up += kBStride2;
    }
    if (valid) {
#pragma unroll
        for (int p = 0; p < kP; ++p) {
            atomicAdd(&sout[(c * kP + p) * kNPOS + n0],     sc.x * acc[p].x);
            atomicAdd(&sout[(c * kP + p) * kNPOS + n0 + 1], sc.y * acc[p].y);
        }
    }
}

__global__ void v1_kernel(float* __restrict__ v0buf,   // holds v0; becomes v0+v1
                          const float* __restrict__ s1)
{
    const int i = blockIdx.x * blockDim.x + threadIdx.x;
    if (i >= kSC) return;
    const int c = i / kNPOS;
    const int n = i - c * kNPOS;
    float sv[kP];
    float nsq = kEPS;
#pragma unroll
    for (int p = 0; p < kP; ++p) {
        const float v = s1[(c * kP + p) * kNPOS + n];
        sv[p] = v;
        nsq = fmaf(v, v, nsq);
    }
    const float inv = 1.f / (1.f + sqrtf(nsq));
#pragma unroll
    for (int p = 0; p < kP; ++p)
        v0buf[(c * kP + p) * kNPOS + n] += sv[p] * inv;  // v0 + v1
}

__global__ void final_kernel(const float* __restrict__ s2, float* __restrict__ out)
{
    const int i = blockIdx.x * blockDim.x + threadIdx.x;
    if (i >= kSC) return;
    const int c = i / kNPOS;
    const int n = i - c * kNPOS;
    const int b = n / kHW;
    const int hw = n - b * kHW;
    float sv[kP];
    float nsq = kEPS;
#pragma unroll
    for (int p = 0; p < kP; ++p) {
        const float v = s2[(c * kP + p) * kNPOS + n];
        sv[p] = v;
        nsq = fmaf(v, v, nsq);
    }
    const float inv = 1.f / (1.f + sqrtf(nsq));
    float vs = 0.f;
#pragma unroll
    for (int p = 0; p < kP; ++p) {
        const float v = sv[p] * inv;
        out[(size_t)((b * kOC + c) * kP + p) * kHW + hw] = v;
        vs = fmaf(v, v, vs);
    }
    out[(size_t)kSCP + (b * kOC + c) * kHW + hw] = sqrtf(vs + kEPS);
}

extern "C" void kernel_launch(void* const* d_in, const int* in_sizes, int n_in,
                              void* d_out, int out_size, void* d_ws, size_t ws_size,
                              hipStream_t stream) {
    const float* U = (const float*)d_in[0];
    float* out = (float*)d_out;
    float* ws  = (float*)d_ws;

    float* s0 = ws;                 // kSCP  (S0, then v0, then v0+v1)
    float* s1 = ws + kSCP;          // kSCP
    float* s2 = ws + 2 * kSCP;      // kSCP
    unsigned int* maxb = (unsigned int*)(ws + 3 * kSCP);   // kSC
    unsigned int* minb = maxb + kSC;                       // kSC
    float* scaleb = (float*)(minb + kSC);                  // kSC

    // re-init scratch every call (ws is poisoned 0xAA before each timed launch)
    hipMemsetAsync(s0, 0, (size_t)3 * kSCP * sizeof(float), stream);
    hipMemsetAsync(maxb, 0, (size_t)kSC * sizeof(unsigned int), stream);     // max init 0
    hipMemsetAsync(minb, 0x7F, (size_t)kSC * sizeof(unsigned int), stream);  // 0x7F7F7F7F = 3.39e38

    pass1_kernel<<<kNBLK, 512, 0, stream>>>(U, s0, maxb, minb);
    v0_kernel<<<(kSC + 255) / 256, 256, 0, stream>>>(s0, maxb, minb, scaleb);
    route_kernel<<<kNBLK, 512, 0, stream>>>(U, s0, scaleb, s1);
    v1_kernel<<<(kSC + 255) / 256, 256, 0, stream>>>(s0, s1);
    route_kernel<<<kNBLK, 512, 0, stream>>>(U, s0, scaleb, s2);
    final_kernel<<<(kSC + 255) / 256, 256, 0, stream>>>(s2, out);
}

// Round 3
// 953.899 us; speedup vs baseline: 1.1195x; 1.0982x over previous
//
#include <hip/hip_runtime.h>

// CapsuleRouting: u (4,288,32,16,14,14) fp32, a unused (dynamic routing variant).
//
// R3 structure: 1 fp32 streaming pass (repack+stats) + 2 bf16 routing passes
// over a 236 MB packed tensor R that fits the 256 MB L3.
//
// pass1 (repack+stats): read U coalesced; per (B,c,pos) norm -> atomic max/min;
//   S0 = sum_B u (atomicAdd); write R = bf16(u) in route-order layout
//   [tile][chunk][Bi][p2][c][j] so every route wave-load is 512 B contiguous.
// v0k  : scale = 1/(max-min); v0 = squash(scale/32 * S0)   [in-place in s0]
// route: r = scale*dot(u, Vr); softmax over C; s += c*scale*u (atomicAdd)
//        (Vr = v0 for iter1; Vr = v0+v1 for iter2: r accumulates dots)
// v1k  : v1 = squash(s1); s0 <- v0+v1
// final: v = squash(s2); out = [v (b,C,P,h,w) | a_out (b,C,h,w)]

constexpr int kIC   = 288;              // input capsules (axis B)
constexpr int kOC   = 32;               // output capsules (axis C)
constexpr int kP    = 16;               // pose
constexpr int kHW   = 196;              // h*w
constexpr int kNPOS = 4 * kHW;          // 784
constexpr int kNT   = 25;               // position tiles of 32 (800, 16 pad)
constexpr int kNCH  = 16;               // B chunks
constexpr int kBCH  = kIC / kNCH;       // 18
constexpr int kSCP  = kOC * kP * kNPOS; // 401408
constexpr int kSC   = kOC * kNPOS;      // 25088
constexpr int kNBLK = kNT * kNCH;       // 400 = 8 * 50
constexpr int kUB   = kOC * kP * kHW;   // U stride per B (floats): 100352
// R geometry (uint2 units): [tile][chunk][Bi 18][p2 8][c 32][j 16]
constexpr int kRslab = kBCH * 8 * kOC * 16;       // uint2 per (tile,chunk): 73728
constexpr size_t kRBytes = (size_t)kNBLK * kRslab * 8;  // 235,929,600 B
constexpr float kEPS = 1e-5f;

// flat block id -> (tile, chunk); XCD g = l&7 gets a contiguous logical range.
__device__ inline void decomp(int l, int& tile, int& chunk) {
    const int logical = (l & 7) * (kNBLK / 8) + (l >> 3);
    tile  = logical >> 4;
    chunk = logical & 15;
}

__device__ inline unsigned bf16rne(float x) {
    const unsigned u = __float_as_uint(x);
    return (u + 0x7FFFu + ((u >> 16) & 1u)) >> 16;
}

__global__ __launch_bounds__(512, 4) void pass1_kernel(
    const float* __restrict__ U, uint2* __restrict__ R, float* __restrict__ s0,
    unsigned int* __restrict__ maxb, unsigned int* __restrict__ minb)
{
    int tile, chunk;
    decomp(blockIdx.x, tile, chunk);
    const int tid = threadIdx.x;
    const int j   = tid & 15;        // 2-position slot
    const int c   = tid >> 4;        // 0..31
    int n0 = tile * 32 + 2 * j;
    const bool valid = (n0 < kNPOS);
    if (!valid) n0 = kNPOS - 2;      // clamp: pad slots hold duplicate data
    const int b  = n0 / kHW;         // 196 % 2 == 0: a pair never straddles b
    const int hw = n0 - b * kHW;
    const int B0 = chunk * kBCH;
    const float* up = U + (size_t)(((b * kIC + B0) * kOC + c) * kP) * kHW + hw;
    uint2* Rp = R + (size_t)(tile * kNCH + chunk) * kRslab + c * 16 + j;

    float2 sacc[kP];
#pragma unroll
    for (int p = 0; p < kP; ++p) sacc[p] = make_float2(0.f, 0.f);
    float2 mx = make_float2(0.f, 0.f);
    float2 mn = make_float2(3.4e38f, 3.4e38f);

    for (int Bi = 0; Bi < kBCH; ++Bi) {
        float2 nsq = make_float2(kEPS, kEPS);
#pragma unroll
        for (int p2 = 0; p2 < 8; ++p2) {
            const float2 a0 = *(const float2*)(up + (2 * p2)     * kHW);
            const float2 a1 = *(const float2*)(up + (2 * p2 + 1) * kHW);
            nsq.x = fmaf(a0.x, a0.x, nsq.x); nsq.y = fmaf(a0.y, a0.y, nsq.y);
            nsq.x = fmaf(a1.x, a1.x, nsq.x); nsq.y = fmaf(a1.y, a1.y, nsq.y);
            sacc[2 * p2].x     += a0.x; sacc[2 * p2].y     += a0.y;
            sacc[2 * p2 + 1].x += a1.x; sacc[2 * p2 + 1].y += a1.y;
            // pack: w.x = (pos0,p) | (pos1,p)<<16 ; w.y = same for p+1
            Rp[(Bi * 8 + p2) * (kOC * 16)] =
                make_uint2(bf16rne(a0.x) | (bf16rne(a0.y) << 16),
                           bf16rne(a1.x) | (bf16rne(a1.y) << 16));
        }
        const float nrx = sqrtf(nsq.x), nry = sqrtf(nsq.y);
        mx.x = fmaxf(mx.x, nrx); mx.y = fmaxf(mx.y, nry);
        mn.x = fminf(mn.x, nrx); mn.y = fminf(mn.y, nry);
        up += kUB;
    }
    if (valid) {
        const int cn = c * kNPOS + n0;
        atomicMax(&maxb[cn],     __float_as_uint(mx.x));  // norms > 0
        atomicMax(&maxb[cn + 1], __float_as_uint(mx.y));
        atomicMin(&minb[cn],     __float_as_uint(mn.x));
        atomicMin(&minb[cn + 1], __float_as_uint(mn.y));
#pragma unroll
        for (int p = 0; p < kP; ++p) {
            atomicAdd(&s0[(c * kP + p) * kNPOS + n0],     sacc[p].x);
            atomicAdd(&s0[(c * kP + p) * kNPOS + n0 + 1], sacc[p].y);
        }
    }
}

__global__ void v0_kernel(float* __restrict__ s0,
                          const unsigned int* __restrict__ maxb,
                          const unsigned int* __restrict__ minb,
                          float* __restrict__ scaleb)
{
    const int i = blockIdx.x * blockDim.x + threadIdx.x; // c*kNPOS + n
    if (i >= kSC) return;
    const int c = i / kNPOS;
    const int n = i - c * kNPOS;
    const float mx = __uint_as_float(maxb[i]);
    const float mn = __uint_as_float(minb[i]);
    const float sc = 1.f / (mx - mn);
    scaleb[i] = sc;
    float sv[kP];
    float nsq = kEPS;
#pragma unroll
    for (int p = 0; p < kP; ++p) {
        const float v = s0[(c * kP + p) * kNPOS + n] * sc * (1.f / 32.f);
        sv[p] = v;
        nsq = fmaf(v, v, nsq);
    }
    const float inv = 1.f / (1.f + sqrtf(nsq));  // squash: s/(1+||s||)
#pragma unroll
    for (int p = 0; p < kP; ++p)
        s0[(c * kP + p) * kNPOS + n] = sv[p] * inv;
}

__global__ __launch_bounds__(512, 3) void route_kernel(
    const uint2* __restrict__ R, const float* __restrict__ Vr,
    const float* __restrict__ scaleb, float* __restrict__ sout)
{
    __shared__ float2 ldsM[8 * 16];
    __shared__ float2 ldsS[8 * 16];
    int tile, chunk;
    decomp(blockIdx.x, tile, chunk);
    const int tid = threadIdx.x;
    const int j   = tid & 15;
    const int c   = tid >> 4;
    const int wv  = tid >> 6;
    int n0 = tile * 32 + 2 * j;
    const bool valid = (n0 < kNPOS);
    if (!valid) n0 = kNPOS - 2;
    const uint2* Rp = R + (size_t)(tile * kNCH + chunk) * kRslab + c * 16 + j;

    float2 vr[kP];
#pragma unroll
    for (int p = 0; p < kP; ++p)
        vr[p] = *(const float2*)&Vr[(c * kP + p) * kNPOS + n0];
    const float2 sc = *(const float2*)&scaleb[c * kNPOS + n0];

    float2 acc[kP];
#pragma unroll
    for (int p = 0; p < kP; ++p) acc[p] = make_float2(0.f, 0.f);

    for (int Bi = 0; Bi < kBCH; ++Bi) {
        float2 u[kP];
#pragma unroll
        for (int p2 = 0; p2 < 8; ++p2) {
            const uint2 w = Rp[(Bi * 8 + p2) * (kOC * 16)];
            u[2 * p2].x     = __uint_as_float(w.x << 16);
            u[2 * p2].y     = __uint_as_float(w.x & 0xFFFF0000u);
            u[2 * p2 + 1].x = __uint_as_float(w.y << 16);
            u[2 * p2 + 1].y = __uint_as_float(w.y & 0xFFFF0000u);
        }
        float2 d = make_float2(0.f, 0.f);
#pragma unroll
        for (int p = 0; p < kP; ++p) {
            d.x = fmaf(u[p].x, vr[p].x, d.x);
            d.y = fmaf(u[p].y, vr[p].y, d.y);
        }
        float2 r = make_float2(sc.x * d.x, sc.y * d.y);

        // softmax over c (32 values): wave = 16 j x 4 c -> shfl, then LDS over 8 waves
        float2 m = r;
        m.x = fmaxf(m.x, __shfl_xor(m.x, 16)); m.y = fmaxf(m.y, __shfl_xor(m.y, 16));
        m.x = fmaxf(m.x, __shfl_xor(m.x, 32)); m.y = fmaxf(m.y, __shfl_xor(m.y, 32));
        if ((tid & 63) < 16) ldsM[wv * 16 + j] = m;
        __syncthreads();
        float2 mxv = ldsM[j];
#pragma unroll
        for (int w = 1; w < 8; ++w) {
            const float2 t = ldsM[w * 16 + j];
            mxv.x = fmaxf(mxv.x, t.x); mxv.y = fmaxf(mxv.y, t.y);
        }
        const float2 e = make_float2(__expf(r.x - mxv.x), __expf(r.y - mxv.y));
        float2 z = e;
        z.x += __shfl_xor(z.x, 16); z.y += __shfl_xor(z.y, 16);
        z.x += __shfl_xor(z.x, 32); z.y += __shfl_xor(z.y, 32);
        if ((tid & 63) < 16) ldsS[wv * 16 + j] = z;
        __syncthreads();
        float2 Z = ldsS[j];
#pragma unroll
        for (int w = 1; w < 8; ++w) {
            const float2 t = ldsS[w * 16 + j];
            Z.x += t.x; Z.y += t.y;
        }
        const float2 cb = make_float2(e.x / Z.x, e.y / Z.y);
#pragma unroll
        for (int p = 0; p < kP; ++p) {
            acc[p].x = fmaf(cb.x, u[p].x, acc[p].x);
            acc[p].y = fmaf(cb.y, u[p].y, acc[p].y);
        }
    }
    if (valid) {
#pragma unroll
        for (int p = 0; p < kP; ++p) {
            atomicAdd(&sout[(c * kP + p) * kNPOS + n0],     sc.x * acc[p].x);
            atomicAdd(&sout[(c * kP + p) * kNPOS + n0 + 1], sc.y * acc[p].y);
        }
    }
}

__global__ void v1_kernel(float* __restrict__ v0buf,   // holds v0; becomes v0+v1
                          const float* __restrict__ s1)
{
    const int i = blockIdx.x * blockDim.x + threadIdx.x;
    if (i >= kSC) return;
    const int c = i / kNPOS;
    const int n = i - c * kNPOS;
    float sv[kP];
    float nsq = kEPS;
#pragma unroll
    for (int p = 0; p < kP; ++p) {
        const float v = s1[(c * kP + p) * kNPOS + n];
        sv[p] = v;
        nsq = fmaf(v, v, nsq);
    }
    const float inv = 1.f / (1.f + sqrtf(nsq));
#pragma unroll
    for (int p = 0; p < kP; ++p)
        v0buf[(c * kP + p) * kNPOS + n] += sv[p] * inv;  // v0 + v1
}

__global__ void final_kernel(const float* __restrict__ s2, float* __restrict__ out)
{
    const int i = blockIdx.x * blockDim.x + threadIdx.x;
    if (i >= kSC) return;
    const int c = i / kNPOS;
    const int n = i - c * kNPOS;
    const int b = n / kHW;
    const int hw = n - b * kHW;
    float sv[kP];
    float nsq = kEPS;
#pragma unroll
    for (int p = 0; p < kP; ++p) {
        const float v = s2[(c * kP + p) * kNPOS + n];
        sv[p] = v;
        nsq = fmaf(v, v, nsq);
    }
    const float inv = 1.f / (1.f + sqrtf(nsq));
    float vs = 0.f;
#pragma unroll
    for (int p = 0; p < kP; ++p) {
        const float v = sv[p] * inv;
        out[(size_t)((b * kOC + c) * kP + p) * kHW + hw] = v;
        vs = fmaf(v, v, vs);
    }
    out[(size_t)kSCP + (b * kOC + c) * kHW + hw] = sqrtf(vs + kEPS);
}

extern "C" void kernel_launch(void* const* d_in, const int* in_sizes, int n_in,
                              void* d_out, int out_size, void* d_ws, size_t ws_size,
                              hipStream_t stream) {
    const float* U = (const float*)d_in[0];
    float* out = (float*)d_out;
    char* wsb  = (char*)d_ws;

    uint2* R   = (uint2*)wsb;                         // 236 MB packed bf16
    float* s0  = (float*)(wsb + kRBytes);             // kSCP (S0 -> v0 -> v0+v1)
    float* s1  = s0 + kSCP;
    float* s2  = s1 + kSCP;
    unsigned int* maxb = (unsigned int*)(s2 + kSCP);  // kSC
    unsigned int* minb = maxb + kSC;                  // kSC
    float* scaleb = (float*)(minb + kSC);             // kSC

    // re-init scratch every call (ws is poisoned 0xAA before each timed launch)
    hipMemsetAsync(s0, 0, (size_t)3 * kSCP * sizeof(float), stream);
    hipMemsetAsync(maxb, 0, (size_t)kSC * sizeof(unsigned int), stream);     // max init 0
    hipMemsetAsync(minb, 0x7F, (size_t)kSC * sizeof(unsigned int), stream);  // 3.39e38

    pass1_kernel<<<kNBLK, 512, 0, stream>>>(U, R, s0, maxb, minb);
    v0_kernel<<<(kSC + 255) / 256, 256, 0, stream>>>(s0, maxb, minb, scaleb);
    route_kernel<<<kNBLK, 512, 0, stream>>>(R, s0, scaleb, s1);
    v1_kernel<<<(kSC + 255) / 256, 256, 0, stream>>>(s0, s1);
    route_kernel<<<kNBLK, 512, 0, stream>>>(R, s0, scaleb, s2);
    final_kernel<<<(kSC + 255) / 256, 256, 0, stream>>>(s2, out);
}